// Round 1
// baseline (165.606 us; speedup 1.0000x reference)
//
#include <hip/hip_runtime.h>
#include <hip/hip_bf16.h>

// Problem constants
#define DIM_X 256
#define DIM_E 256
#define DD    512          // DIM_X + DIM_E
#define NB    8            // batch
#define NN    2048         // sequence
#define SCALE 0.044194173824159216f   // (DIM_X+DIM_E)^-0.5
#define GRID  512          // fused grid: 2 blocks/CU * 256 CU, fully resident

typedef __attribute__((ext_vector_type(8))) __bf16 bf16x8;
typedef __attribute__((ext_vector_type(4))) float  f32x4;
using bf16 = __hip_bfloat16;

__device__ __forceinline__ unsigned short f2bf(float f) {
  union { __hip_bfloat16 h; unsigned short u; } c;
  c.h = __float2bfloat16(f);
  return c.u;
}

// async global->LDS 16B copy. LDS dest must be wave-uniform base + lane*16.
__device__ __forceinline__ void async_lds16(const void* g, void* l) {
  using u32_as3 = __attribute__((address_space(3))) unsigned int;
  using u32_as1 = const __attribute__((address_space(1))) unsigned int;
  __builtin_amdgcn_global_load_lds(
      reinterpret_cast<u32_as1*>(reinterpret_cast<unsigned long long>(g)),
      reinterpret_cast<u32_as3*>(static_cast<unsigned int>(
          reinterpret_cast<unsigned long long>(l))),
      16, 0, 0);
}

// ---------------------------------------------------------------------------
// Grid-wide barrier. Sense-reversing, state in __device__ globals so it is
// self-restoring across graph replays (count returns to 0, sense flips; no
// host-side reset needed and harness workspace re-poisoning can't touch it).
// Residency guarantee for GRID=512: __launch_bounds__(256,2) forces >=2
// blocks/CU (VGPR side) and 48KB LDS allows 3/CU, so all 512 co-resident.
// Cross-XCD visibility: arrival RMW is ACQ_REL agent-scope (buffer_wbl2
// before / buffer_inv after on gfx950); waiters poll relaxed (with an
// every-64th fetch_add(0) that is forced to the coherence point, so the
// loop cannot spin on a stale local-L2 line) then do one acquire fence.
// ---------------------------------------------------------------------------
__device__ __align__(128) unsigned g_cnt   = 0u;
__device__ __align__(128) unsigned g_sense = 0u;

__device__ __forceinline__ void grid_sync() {
  __syncthreads();  // all waves drain vmem (compiler emits vmcnt(0) here)
  if (threadIdx.x == 0) {
    unsigned s = __hip_atomic_load(&g_sense, __ATOMIC_RELAXED,
                                   __HIP_MEMORY_SCOPE_AGENT);
    unsigned prev = __hip_atomic_fetch_add(&g_cnt, 1u, __ATOMIC_ACQ_REL,
                                           __HIP_MEMORY_SCOPE_AGENT);
    if (prev == (unsigned)(GRID - 1)) {
      __hip_atomic_store(&g_cnt, 0u, __ATOMIC_RELAXED,
                         __HIP_MEMORY_SCOPE_AGENT);
      __hip_atomic_store(&g_sense, s ^ 1u, __ATOMIC_RELEASE,
                         __HIP_MEMORY_SCOPE_AGENT);
    } else {
      unsigned n = 0;
      for (;;) {
        unsigned v = ((++n) & 63u)
                         ? __hip_atomic_load(&g_sense, __ATOMIC_RELAXED,
                                             __HIP_MEMORY_SCOPE_AGENT)
                         : __hip_atomic_fetch_add(&g_sense, 0u,
                                                  __ATOMIC_RELAXED,
                                                  __HIP_MEMORY_SCOPE_AGENT);
        if (v != s) break;
        __builtin_amdgcn_s_sleep(4);
      }
      __builtin_amdgcn_fence(__ATOMIC_ACQUIRE, "agent");
    }
  }
  __syncthreads();
}

// ---------------------------------------------------------------------------
// One BMxBN tile of C = alpha * Acat @ Bcat^T (operands K-major bf16).
// 4 waves 2x2, wave tile (BM/2)x(BN/2), 16x16x32 MFMA, XOR-swizzled LDS,
// global_load_lds width-16 staging, K-tile BKt.
// ASPLIT>0: for k>=ASPLIT read A1 at k-ASPLIT (K-concatenation of A0|A1).
// BSPLIT>0: same for B0|B1. (B1==B0 gives a K-repeated B.)
// ---------------------------------------------------------------------------
template <int BM, int BN, int BKt, bool OUT_BF16, int ASPLIT, int BSPLIT>
__device__ void gemm_tile(const bf16* __restrict__ A0,
                          const bf16* __restrict__ A1,
                          const bf16* __restrict__ B0,
                          const bf16* __restrict__ B1, void* __restrict__ Cv,
                          int K, int lda, int ldb, int ldc, float alpha,
                          char* smem) {
  constexpr int CPT = BKt / 8;       // 16B chunks per row
  constexpr int KS  = BKt / 32;      // MFMA k-steps per staged tile
  constexpr int WTM = BM / 2, WTN = BN / 2;
  constexpr int IM = WTM / 16, IN = WTN / 16;
  constexpr int CA = BM * CPT, CB = BN * CPT;
  bf16* sA = (bf16*)smem;
  bf16* sB = (bf16*)(smem + (size_t)BM * BKt * 2);

  const int tid  = threadIdx.x;
  const int lane = tid & 63;
  const int wave = tid >> 6;
  const int lm   = lane & 15;
  const int quad = lane >> 4;
  const int wm   = (wave >> 1) * WTM;
  const int wn   = (wave & 1) * WTN;

  f32x4 acc[IM][IN];
#pragma unroll
  for (int i = 0; i < IM; i++)
#pragma unroll
    for (int j = 0; j < IN; j++) acc[i][j] = (f32x4){0.f, 0.f, 0.f, 0.f};

  for (int k0 = 0; k0 < K; k0 += BKt) {
    const bf16* Ak = A0; int ka = k0;
    if (ASPLIT > 0 && k0 >= ASPLIT) { Ak = A1; ka = k0 - ASPLIT; }
    const bf16* Bk = B0; int kb = k0;
    if (BSPLIT > 0 && k0 >= BSPLIT) { Bk = B1; kb = k0 - BSPLIT; }
#pragma unroll
    for (int c = tid; c < CA; c += 256) {
      int row = c / CPT;
      int cb  = (c % CPT) ^ (row % CPT);
      async_lds16(Ak + (long)row * lda + ka + cb * 8, sA + (size_t)c * 8);
    }
#pragma unroll
    for (int c = tid; c < CB; c += 256) {
      int row = c / CPT;
      int cb  = (c % CPT) ^ (row % CPT);
      async_lds16(Bk + (long)row * ldb + kb + cb * 8, sB + (size_t)c * 8);
    }
    __syncthreads();  // drains vmcnt (global_load_lds)

    bf16x8 af[KS][IM], bfr[KS][IN];
#pragma unroll
    for (int s = 0; s < KS; s++) {
#pragma unroll
      for (int i = 0; i < IM; i++) {
        int r = wm + i * 16 + lm;
        af[s][i] = *(const bf16x8*)&sA[r * BKt +
                                       (((s * 4 + quad) ^ (r % CPT)) * 8)];
      }
#pragma unroll
      for (int j = 0; j < IN; j++) {
        int r = wn + j * 16 + lm;
        bfr[s][j] = *(const bf16x8*)&sB[r * BKt +
                                        (((s * 4 + quad) ^ (r % CPT)) * 8)];
      }
    }
#pragma unroll
    for (int s = 0; s < KS; s++)
#pragma unroll
      for (int i = 0; i < IM; i++)
#pragma unroll
        for (int j = 0; j < IN; j++)
          acc[i][j] = __builtin_amdgcn_mfma_f32_16x16x32_bf16(
              af[s][i], bfr[s][j], acc[i][j], 0, 0, 0);
    __syncthreads();
  }

  // C/D layout (16x16): col = lane&15, row = (lane>>4)*4 + reg  [m89-verified]
  const int baseRow = wm + quad * 4;
  const int baseCol = wn + lm;
  if (OUT_BF16) {
    bf16* Cb = (bf16*)Cv;
#pragma unroll
    for (int i = 0; i < IM; i++)
#pragma unroll
      for (int r = 0; r < 4; r++) {
        int row = baseRow + i * 16 + r;
#pragma unroll
        for (int j = 0; j < IN; j++)
          Cb[(long)row * ldc + baseCol + j * 16] =
              __float2bfloat16(acc[i][j][r] * alpha);
      }
  } else {
    float* Cf = (float*)Cv;
#pragma unroll
    for (int i = 0; i < IM; i++)
#pragma unroll
      for (int r = 0; r < 4; r++) {
        int row = baseRow + i * 16 + r;
#pragma unroll
        for (int j = 0; j < IN; j++)
          Cf[(long)row * ldc + baseCol + j * 16] = acc[i][j][r] * alpha;
      }
  }
}

// ---------------------------------------------------------------------------
// Fused pipeline, one launch, 512 blocks, 3 grid barriers:
//   phase0 pack : 5120 32x32 tile jobs (bf16 casts + transposes), 10/block
//   phase1      : M half-K partials, 64x64 tiles (16 MFMA/wave/iter vs 8 at
//                 the old 32x64), 512 jobs: (b,mt,nt,kh) K=1024 each;
//                 + 64 W2T jobs (64x64, K=512) spread bx = 8k+(k&7)
//   phase2      : R = SCALE*(M1+M2)@W2T^T as K-concat GEMM K=1024
//                 ([M1|M2] @ [W2T|W2T]^T) via ASPLIT/BSPLIT=512
//   phase3      : out = [xb|eb] @ R^T, 64x128 tiles, fp32 out (unchanged)
// XCD affinity: b = bx&7 throughout, so VT_b / M_b stay in one XCD's L2.
// ---------------------------------------------------------------------------
__global__ __launch_bounds__(256, 2) void fused_k(
    const float* __restrict__ x, const float* __restrict__ e,
    const float* __restrict__ Wq, const float* __restrict__ Wk,
    bf16* __restrict__ xb, bf16* __restrict__ VT, bf16* __restrict__ eb,
    bf16* __restrict__ ET, bf16* __restrict__ WqT, bf16* __restrict__ WkT,
    bf16* __restrict__ W2T, bf16* __restrict__ M1, bf16* __restrict__ M2,
    bf16* __restrict__ R, float* __restrict__ out) {
  __shared__ __align__(16) char smem[49152];
  const int bx  = blockIdx.x;
  const int tid = threadIdx.x;

  // ---- phase 0: pack -----------------------------------------------------
  {
    float (*tile)[33] = reinterpret_cast<float (*)[33]>(smem);
    const int lrow = tid >> 3;        // 0..31
    const int lc4  = (tid & 7) * 4;   // float4 col
    for (int j = bx; j < 5120; j += GRID) {
      const float* src; int ld;
      bf16 *dS = nullptr, *dT; int ldS = 0, ldT;
      if (j < 4096) {
        int b = j >> 9, r = (j >> 3) & 63, c = j & 7;
        src = x + ((long)b * NN + r * 32) * DIM_X + c * 32; ld = DIM_X;
        dS = xb + ((long)b * NN + r * 32) * DIM_X + c * 32; ldS = DIM_X;
        dT = VT + ((long)b * DIM_X + c * 32) * NN + r * 32; ldT = NN;
      } else if (j < 4608) {
        int i = j - 4096, r = i >> 3, c = i & 7;
        src = e + ((long)r * 32) * DIM_E + c * 32; ld = DIM_E;
        dS = eb + ((long)r * 32) * DIM_E + c * 32; ldS = DIM_E;
        dT = ET + ((long)c * 32) * NN + r * 32; ldT = NN;
      } else if (j < 4864) {
        int i = j - 4608, r = i >> 4, c = i & 15;
        src = Wq + ((long)r * 32) * DD + c * 32; ld = DD;
        dT = WqT + ((long)c * 32) * DD + r * 32; ldT = DD;
      } else {
        int i = j - 4864, r = i >> 4, c = i & 15;
        src = Wk + ((long)r * 32) * DD + c * 32; ld = DD;
        dT = WkT + ((long)c * 32) * DD + r * 32; ldT = DD;
      }
      float4 v = *(const float4*)(src + (long)lrow * ld + lc4);
      if (dS) {
        ushort4 o;
        o.x = f2bf(v.x); o.y = f2bf(v.y); o.z = f2bf(v.z); o.w = f2bf(v.w);
        *(ushort4*)((unsigned short*)dS + (long)lrow * ldS + lc4) = o;
      }
      tile[lrow][lc4 + 0] = v.x; tile[lrow][lc4 + 1] = v.y;
      tile[lrow][lc4 + 2] = v.z; tile[lrow][lc4 + 3] = v.w;
      __syncthreads();
      {
        ushort4 o;
        o.x = f2bf(tile[lc4 + 0][lrow]);
        o.y = f2bf(tile[lc4 + 1][lrow]);
        o.z = f2bf(tile[lc4 + 2][lrow]);
        o.w = f2bf(tile[lc4 + 3][lrow]);
        *(ushort4*)((unsigned short*)dT + (long)lrow * ldT + lc4) = o;
      }
      __syncthreads();
    }
  }
  grid_sync();

  // ---- phase 1: M split-K partials + W2T ---------------------------------
  {
    const int b   = bx & 7;
    const int idx = bx >> 3;              // 0..63
    const int kh  = idx & 1;              // K half
    const int mt  = (idx >> 1) & 3;       // row tile (4 x 64 = 256)
    const int nt  = idx >> 3;             // col tile (8 x 64 = 512)
    const bf16* A = VT + (long)b * DIM_X * NN + (long)mt * 64 * NN + kh * 1024;
    const bf16* B = (nt < 4)
        ? VT + (long)b * DIM_X * NN + (long)nt * 64 * NN + kh * 1024
        : ET + (long)(nt - 4) * 64 * NN + kh * 1024;
    bf16* C = (kh ? M2 : M1) + (long)b * DIM_X * DD + (long)mt * 64 * DD +
              nt * 64;
    gemm_tile<64, 64, 128, true, 0, 0>(A, nullptr, B, nullptr, C, 1024, NN,
                                       NN, DD, 1.0f, smem);
    const int k = bx >> 3;                // W2 job id candidate
    if ((bx & 7) == (k & 7)) {            // exactly one block per k, spread
      int r2 = k >> 3, c2 = k & 7;
      gemm_tile<64, 64, 128, true, 0, 0>(
          WqT + (long)r2 * 64 * DD, nullptr, WkT + (long)c2 * 64 * DD,
          nullptr, W2T + (long)r2 * 64 * DD + c2 * 64, DD, DD, DD, DD, 1.0f,
          smem);
    }
  }
  grid_sync();

  // ---- phase 2: R = SCALE * (M1+M2) @ W2T^T  (K-concat, K=1024) ----------
  {
    const int b = bx & 7, r = (bx >> 3) & 7, c = bx >> 6;
    const bf16* a0 = M1 + (long)b * DIM_X * DD + (long)r * 32 * DD;
    const bf16* a1 = M2 + (long)b * DIM_X * DD + (long)r * 32 * DD;
    const bf16* w  = W2T + (long)c * 64 * DD;
    gemm_tile<32, 64, 128, true, 512, 512>(
        a0, a1, w, w,
        R + (long)b * DIM_X * DD + (long)r * 32 * DD + c * 64, 1024, DD, DD,
        DD, SCALE, smem);
  }
  grid_sync();

  // ---- phase 3: out = [xb|eb] @ R^T  (fp32 out) --------------------------
  {
    const int b = bx & 7, m = (bx >> 3) & 31, n = (bx >> 8) & 1;
    gemm_tile<64, 128, 128, false, 256, 0>(
        xb + (long)b * NN * DIM_X + (long)m * 64 * DIM_X,
        eb + (long)m * 64 * DIM_E,
        R + (long)b * DIM_X * DD + (long)n * 128 * DD, nullptr,
        out + (long)b * NN * DIM_X + (long)m * 64 * DIM_X + n * 128, DD,
        DIM_X, DD, DIM_X, 1.0f, smem);
  }
}

// ---------------------------------------------------------------------------

extern "C" void kernel_launch(void* const* d_in, const int* in_sizes, int n_in,
                              void* d_out, int out_size, void* d_ws,
                              size_t ws_size, hipStream_t stream) {
  const float* x  = (const float*)d_in[0];  // (8, 2048, 256)
  const float* e  = (const float*)d_in[1];  // (2048, 256)
  const float* Wq = (const float*)d_in[2];  // (512, 512)
  const float* Wk = (const float*)d_in[3];  // (512, 512)
  float* out = (float*)d_out;               // (8, 2048, 256)

  char* ws = (char*)d_ws;
  size_t off = 0;
  auto alloc = [&](size_t bytes) {
    void* p = ws + off;
    off += (bytes + 255) & ~(size_t)255;
    return p;
  };

  bf16* xb  = (bf16*)alloc((size_t)NB * NN * DIM_X * 2);  // 8.4 MB
  bf16* VT  = (bf16*)alloc((size_t)NB * DIM_X * NN * 2);  // 8.4 MB
  bf16* eb  = (bf16*)alloc((size_t)NN * DIM_E * 2);       // 1 MB
  bf16* ET  = (bf16*)alloc((size_t)DIM_E * NN * 2);       // 1 MB
  bf16* WqT = (bf16*)alloc((size_t)DD * DD * 2);          // 0.5 MB
  bf16* WkT = (bf16*)alloc((size_t)DD * DD * 2);          // 0.5 MB
  bf16* W2T = (bf16*)alloc((size_t)DD * DD * 2);          // 0.5 MB
  bf16* M1  = (bf16*)alloc((size_t)NB * DIM_X * DD * 2);  // 2 MB
  bf16* M2  = (bf16*)alloc((size_t)NB * DIM_X * DD * 2);  // 2 MB
  bf16* R   = (bf16*)alloc((size_t)NB * DIM_X * DD * 2);  // 2 MB

  fused_k<<<GRID, 256, 0, stream>>>(x, e, Wq, Wk, xb, VT, eb, ET, WqT, WkT,
                                    W2T, M1, M2, R, out);
}

// Round 2
// 105.991 us; speedup vs baseline: 1.5625x; 1.5625x over previous
//
#include <hip/hip_runtime.h>
#include <hip/hip_bf16.h>

// Problem constants
#define DIM_X 256
#define DIM_E 256
#define DD    512          // DIM_X + DIM_E
#define NB    8            // batch
#define NN    2048         // sequence
#define SCALE 0.044194173824159216f   // (DIM_X+DIM_E)^-0.5

typedef __attribute__((ext_vector_type(8))) __bf16 bf16x8;
typedef __attribute__((ext_vector_type(4))) float  f32x4;
using bf16 = __hip_bfloat16;

__device__ __forceinline__ unsigned short f2bf(float f) {
  union { __hip_bfloat16 h; unsigned short u; } c;
  c.h = __float2bfloat16(f);
  return c.u;
}

// async global->LDS 16B copy. LDS dest must be wave-uniform base + lane*16.
__device__ __forceinline__ void async_lds16(const void* g, void* l) {
  using u32_as3 = __attribute__((address_space(3))) unsigned int;
  using u32_as1 = const __attribute__((address_space(1))) unsigned int;
  __builtin_amdgcn_global_load_lds(
      reinterpret_cast<u32_as1*>(reinterpret_cast<unsigned long long>(g)),
      reinterpret_cast<u32_as3*>(static_cast<unsigned int>(
          reinterpret_cast<unsigned long long>(l))),
      16, 0, 0);
}

// ---------------------------------------------------------------------------
// pack: 5120 32x32-tile jobs, ONE per block (max parallelism / HBM queue
// depth; round-0's 5-job serial chain per block removed):
//   jobs [0,4096):     x -> xb (straight bf16) + VT (transpose)
//   jobs [4096,4608):  e -> eb (straight) + ET (transpose)
//   jobs [4608,4864):  Wq -> WqT (transpose)
//   jobs [4864,5120):  Wk -> WkT (transpose)
// ---------------------------------------------------------------------------
__global__ __launch_bounds__(256, 4) void pack_k(
    const float* __restrict__ x, const float* __restrict__ e,
    const float* __restrict__ Wq, const float* __restrict__ Wk, bf16* xb,
    bf16* VT, bf16* eb, bf16* ET, bf16* WqT, bf16* WkT) {
  __shared__ float tile[32][33];
  const int tid  = threadIdx.x;
  const int lrow = tid >> 3;        // 0..31 (load row)
  const int lc4  = (tid & 7) * 4;   // float4 col
  const int j    = blockIdx.x;
  const float* src; int ld;
  bf16 *dS = nullptr, *dT; int ldS = 0, ldT;
  if (j < 4096) {
    int b = j >> 9, r = (j >> 3) & 63, c = j & 7;
    src = x + ((long)b * NN + r * 32) * DIM_X + c * 32; ld = DIM_X;
    dS = xb + ((long)b * NN + r * 32) * DIM_X + c * 32; ldS = DIM_X;
    dT = VT + ((long)b * DIM_X + c * 32) * NN + r * 32; ldT = NN;
  } else if (j < 4608) {
    int i = j - 4096, r = i >> 3, c = i & 7;
    src = e + ((long)r * 32) * DIM_E + c * 32; ld = DIM_E;
    dS = eb + ((long)r * 32) * DIM_E + c * 32; ldS = DIM_E;
    dT = ET + ((long)c * 32) * NN + r * 32; ldT = NN;
  } else if (j < 4864) {
    int i = j - 4608, r = i >> 4, c = i & 15;
    src = Wq + ((long)r * 32) * DD + c * 32; ld = DD;
    dT = WqT + ((long)c * 32) * DD + r * 32; ldT = DD;
  } else {
    int i = j - 4864, r = i >> 4, c = i & 15;
    src = Wk + ((long)r * 32) * DD + c * 32; ld = DD;
    dT = WkT + ((long)c * 32) * DD + r * 32; ldT = DD;
  }
  float4 v = *(const float4*)(src + (long)lrow * ld + lc4);
  if (dS) {
    ushort4 o;
    o.x = f2bf(v.x); o.y = f2bf(v.y); o.z = f2bf(v.z); o.w = f2bf(v.w);
    *(ushort4*)((unsigned short*)dS + (long)lrow * ldS + lc4) = o;
  }
  tile[lrow][lc4 + 0] = v.x; tile[lrow][lc4 + 1] = v.y;
  tile[lrow][lc4 + 2] = v.z; tile[lrow][lc4 + 3] = v.w;
  __syncthreads();
  {
    ushort4 o;
    o.x = f2bf(tile[lc4 + 0][lrow]);
    o.y = f2bf(tile[lc4 + 1][lrow]);
    o.z = f2bf(tile[lc4 + 2][lrow]);
    o.w = f2bf(tile[lc4 + 3][lrow]);
    *(ushort4*)((unsigned short*)dT + (long)lrow * ldT + lc4) = o;
  }
}

// ---------------------------------------------------------------------------
// One BMxBN tile of C = alpha * Acat @ Bcat^T (operands K-major bf16).
// 4 waves 2x2, wave tile (BM/2)x(BN/2), 16x16x32 MFMA, XOR-swizzled LDS,
// global_load_lds width-16 staging.
// T3 minimal 2-phase: double-buffered LDS, stage(t+1) issued BEFORE the
// ds_read+MFMA of tile t, ONE barrier per K-step (its vmcnt(0) drains the
// prefetch whose latency hid under this tile's compute).
// ASPLIT>0: for k>=ASPLIT read A1 at k-ASPLIT (K-concatenation of A0|A1).
// BSPLIT>0: same for B0|B1 (B1==B0 gives a K-repeated B).
// smem must be 2*(BM+BN)*BKt*2 bytes.
// ---------------------------------------------------------------------------
template <int BM, int BN, int BKt, bool OUT_BF16, int ASPLIT, int BSPLIT>
__device__ void gemm_tile(const bf16* __restrict__ A0,
                          const bf16* __restrict__ A1,
                          const bf16* __restrict__ B0,
                          const bf16* __restrict__ B1, void* __restrict__ Cv,
                          int K, int lda, int ldb, int ldc, float alpha,
                          char* smem) {
  constexpr int CPT  = BKt / 8;      // 16B chunks per row
  constexpr int KS   = BKt / 32;     // MFMA k-steps per staged tile
  constexpr int WTM  = BM / 2, WTN = BN / 2;
  constexpr int IM   = WTM / 16, IN = WTN / 16;
  constexpr int CA   = BM * CPT, CB = BN * CPT;
  constexpr int BUFB = (BM + BN) * BKt * 2;  // bytes per LDS buffer

  const int tid  = threadIdx.x;
  const int lane = tid & 63;
  const int wave = tid >> 6;
  const int lm   = lane & 15;
  const int quad = lane >> 4;
  const int wm   = (wave >> 1) * WTM;
  const int wn   = (wave & 1) * WTN;

  auto stage = [&](int t, int buf) {
    const int k0 = t * BKt;
    const bf16* Ak = A0; int ka = k0;
    if (ASPLIT > 0 && k0 >= ASPLIT) { Ak = A1; ka = k0 - ASPLIT; }
    const bf16* Bk = B0; int kb = k0;
    if (BSPLIT > 0 && k0 >= BSPLIT) { Bk = B1; kb = k0 - BSPLIT; }
    bf16* sA = (bf16*)(smem + (size_t)buf * BUFB);
    bf16* sB = sA + BM * BKt;
#pragma unroll
    for (int c = tid; c < CA; c += 256) {
      int row = c / CPT;
      int cb  = (c % CPT) ^ (row % CPT);
      async_lds16(Ak + (long)row * lda + ka + cb * 8, sA + (size_t)c * 8);
    }
#pragma unroll
    for (int c = tid; c < CB; c += 256) {
      int row = c / CPT;
      int cb  = (c % CPT) ^ (row % CPT);
      async_lds16(Bk + (long)row * ldb + kb + cb * 8, sB + (size_t)c * 8);
    }
  };

  f32x4 acc[IM][IN];
#pragma unroll
  for (int i = 0; i < IM; i++)
#pragma unroll
    for (int j = 0; j < IN; j++) acc[i][j] = (f32x4){0.f, 0.f, 0.f, 0.f};

  const int nt = K / BKt;
  stage(0, 0);
  __syncthreads();  // drains vmcnt(0): tile 0 resident
  int cur = 0;
  for (int t = 0; t < nt; ++t) {
    if (t + 1 < nt) stage(t + 1, cur ^ 1);  // prefetch overlaps compute below
    const bf16* sA = (const bf16*)(smem + (size_t)cur * BUFB);
    const bf16* sB = sA + BM * BKt;
    bf16x8 af[KS][IM], bfr[KS][IN];
#pragma unroll
    for (int s = 0; s < KS; s++) {
#pragma unroll
      for (int i = 0; i < IM; i++) {
        int r = wm + i * 16 + lm;
        af[s][i] = *(const bf16x8*)&sA[r * BKt +
                                       (((s * 4 + quad) ^ (r % CPT)) * 8)];
      }
#pragma unroll
      for (int j = 0; j < IN; j++) {
        int r = wn + j * 16 + lm;
        bfr[s][j] = *(const bf16x8*)&sB[r * BKt +
                                        (((s * 4 + quad) ^ (r % CPT)) * 8)];
      }
    }
#pragma unroll
    for (int s = 0; s < KS; s++)
#pragma unroll
      for (int i = 0; i < IM; i++)
#pragma unroll
        for (int j = 0; j < IN; j++)
          acc[i][j] = __builtin_amdgcn_mfma_f32_16x16x32_bf16(
              af[s][i], bfr[s][j], acc[i][j], 0, 0, 0);
    __syncthreads();  // readers done with buf cur; prefetch into cur^1 drained
    cur ^= 1;
  }

  // C/D layout (16x16): col = lane&15, row = (lane>>4)*4 + reg  [m89-verified]
  const int baseRow = wm + quad * 4;
  const int baseCol = wn + lm;
  if (OUT_BF16) {
    bf16* Cb = (bf16*)Cv;
#pragma unroll
    for (int i = 0; i < IM; i++)
#pragma unroll
      for (int r = 0; r < 4; r++) {
        int row = baseRow + i * 16 + r;
#pragma unroll
        for (int j = 0; j < IN; j++)
          Cb[(long)row * ldc + baseCol + j * 16] =
              __float2bfloat16(acc[i][j][r] * alpha);
      }
  } else {
    float* Cf = (float*)Cv;
#pragma unroll
    for (int i = 0; i < IM; i++)
#pragma unroll
      for (int r = 0; r < 4; r++) {
        int row = baseRow + i * 16 + r;
#pragma unroll
        for (int j = 0; j < IN; j++)
          Cf[(long)row * ldc + baseCol + j * 16] = acc[i][j][r] * alpha;
      }
  }
}

// ---------------------------------------------------------------------------
// phase1 (576 blocks, all co-resident at 4/CU, LDS 32KB dbuf):
//   blocks [0,64):   W2T = WqT @ WkT^T (64x64, K=512) — own blocks, no
//                    serial imbalance with M jobs
//   blocks [64,576): M half-K partials, 64x64 tiles (16 MFMA/staged tile),
//                    512 jobs (b, mt, nt, kh), K=1024 each, split-K reduced
//                    in phase2 via K-concat. b = bx&7 keeps XCD affinity.
// ---------------------------------------------------------------------------
__global__ __launch_bounds__(256, 4) void phase1_k(
    const bf16* VT, const bf16* ET, const bf16* WqT, const bf16* WkT,
    bf16* M1, bf16* M2, bf16* W2T) {
  __shared__ __align__(16) char smem[32768];
  const int bx = blockIdx.x;
  if (bx < 64) {
    int r2 = bx >> 3, c2 = bx & 7;
    gemm_tile<64, 64, 64, true, 0, 0>(
        WqT + (long)r2 * 64 * DD, nullptr, WkT + (long)c2 * 64 * DD, nullptr,
        W2T + (long)r2 * 64 * DD + c2 * 64, DD, DD, DD, DD, 1.0f, smem);
  } else {
    const int j   = bx - 64;
    const int b   = j & 7;
    const int idx = j >> 3;               // 0..63
    const int kh  = idx & 1;              // K half
    const int mt  = (idx >> 1) & 3;       // row tile (4 x 64 = 256)
    const int nt  = idx >> 3;             // col tile (8 x 64 = 512)
    const bf16* A = VT + (long)b * DIM_X * NN + (long)mt * 64 * NN + kh * 1024;
    const bf16* B = (nt < 4)
        ? VT + (long)b * DIM_X * NN + (long)nt * 64 * NN + kh * 1024
        : ET + (long)(nt - 4) * 64 * NN + kh * 1024;
    bf16* C = (kh ? M2 : M1) + (long)b * DIM_X * DD + (long)mt * 64 * DD +
              nt * 64;
    gemm_tile<64, 64, 64, true, 0, 0>(A, nullptr, B, nullptr, C, 1024, NN,
                                      NN, DD, 1.0f, smem);
  }
}

// ---------------------------------------------------------------------------
// phase2 (512 blocks): R = SCALE * (M1+M2) @ W2T^T as K-concat GEMM K=1024
// ([M1|M2] @ [W2T|W2T]^T, ASPLIT=BSPLIT=512; verified correct in round 1).
// 32x64 tiles, BK=128 dbuf (48KB), all resident at 2/CU.
// ---------------------------------------------------------------------------
__global__ __launch_bounds__(256, 3) void phase2_k(const bf16* M1,
                                                   const bf16* M2,
                                                   const bf16* W2T, bf16* R) {
  __shared__ __align__(16) char smem[49152];
  const int bx = blockIdx.x;
  const int b = bx & 7, r = (bx >> 3) & 7, c = bx >> 6;
  const bf16* a0 = M1 + (long)b * DIM_X * DD + (long)r * 32 * DD;
  const bf16* a1 = M2 + (long)b * DIM_X * DD + (long)r * 32 * DD;
  const bf16* w  = W2T + (long)c * 64 * DD;
  gemm_tile<32, 64, 128, true, 512, 512>(
      a0, a1, w, w, R + (long)b * DIM_X * DD + (long)r * 32 * DD + c * 64,
      1024, DD, DD, DD, SCALE, smem);
}

// ---------------------------------------------------------------------------
// phase3 (512 blocks): out = [xb|eb] @ R^T, 64x128 tiles, BK=64 dbuf (48KB),
// fp32 out, all resident at 2/CU. XCD-affine b = bx&7 (R_b L2-local).
// ---------------------------------------------------------------------------
__global__ __launch_bounds__(256, 3) void phase3_k(const bf16* xb,
                                                   const bf16* eb,
                                                   const bf16* R, float* out) {
  __shared__ __align__(16) char smem[49152];
  const int bx = blockIdx.x;
  const int b = bx & 7, m = (bx >> 3) & 31, n = (bx >> 8) & 1;
  gemm_tile<64, 128, 64, false, 256, 0>(
      xb + (long)b * NN * DIM_X + (long)m * 64 * DIM_X,
      eb + (long)m * 64 * DIM_E,
      R + (long)b * DIM_X * DD + (long)n * 128 * DD, nullptr,
      out + (long)b * NN * DIM_X + (long)m * 64 * DIM_X + n * 128, DD, DIM_X,
      DD, DIM_X, 1.0f, smem);
}

// ---------------------------------------------------------------------------

extern "C" void kernel_launch(void* const* d_in, const int* in_sizes, int n_in,
                              void* d_out, int out_size, void* d_ws,
                              size_t ws_size, hipStream_t stream) {
  const float* x  = (const float*)d_in[0];  // (8, 2048, 256)
  const float* e  = (const float*)d_in[1];  // (2048, 256)
  const float* Wq = (const float*)d_in[2];  // (512, 512)
  const float* Wk = (const float*)d_in[3];  // (512, 512)
  float* out = (float*)d_out;               // (8, 2048, 256)

  char* ws = (char*)d_ws;
  size_t off = 0;
  auto alloc = [&](size_t bytes) {
    void* p = ws + off;
    off += (bytes + 255) & ~(size_t)255;
    return p;
  };

  bf16* xb  = (bf16*)alloc((size_t)NB * NN * DIM_X * 2);  // 8.4 MB
  bf16* VT  = (bf16*)alloc((size_t)NB * DIM_X * NN * 2);  // 8.4 MB
  bf16* eb  = (bf16*)alloc((size_t)NN * DIM_E * 2);       // 1 MB
  bf16* ET  = (bf16*)alloc((size_t)DIM_E * NN * 2);       // 1 MB
  bf16* WqT = (bf16*)alloc((size_t)DD * DD * 2);          // 0.5 MB
  bf16* WkT = (bf16*)alloc((size_t)DD * DD * 2);          // 0.5 MB
  bf16* W2T = (bf16*)alloc((size_t)DD * DD * 2);          // 0.5 MB
  bf16* M1  = (bf16*)alloc((size_t)NB * DIM_X * DD * 2);  // 2 MB
  bf16* M2  = (bf16*)alloc((size_t)NB * DIM_X * DD * 2);  // 2 MB
  bf16* R   = (bf16*)alloc((size_t)NB * DIM_X * DD * 2);  // 2 MB

  pack_k<<<5120, 256, 0, stream>>>(x, e, Wq, Wk, xb, VT, eb, ET, WqT, WkT);
  phase1_k<<<576, 256, 0, stream>>>(VT, ET, WqT, WkT, M1, M2, W2T);
  phase2_k<<<512, 256, 0, stream>>>(M1, M2, W2T, R);
  phase3_k<<<512, 256, 0, stream>>>(xb, eb, R, out);
}

// Round 3
// 105.064 us; speedup vs baseline: 1.5763x; 1.0088x over previous
//
#include <hip/hip_runtime.h>
#include <hip/hip_bf16.h>

// Problem constants
#define DIM_X 256
#define DIM_E 256
#define DD    512          // DIM_X + DIM_E
#define NB    8            // batch
#define NN    2048         // sequence
#define SCALE 0.044194173824159216f   // (DIM_X+DIM_E)^-0.5

typedef __attribute__((ext_vector_type(8))) __bf16 bf16x8;
typedef __attribute__((ext_vector_type(4))) float  f32x4;
using bf16 = __hip_bfloat16;

__device__ __forceinline__ unsigned short f2bf(float f) {
  union { __hip_bfloat16 h; unsigned short u; } c;
  c.h = __float2bfloat16(f);
  return c.u;
}

// async global->LDS 16B copy. LDS dest must be wave-uniform base + lane*16.
__device__ __forceinline__ void async_lds16(const void* g, void* l) {
  using u32_as3 = __attribute__((address_space(3))) unsigned int;
  using u32_as1 = const __attribute__((address_space(1))) unsigned int;
  __builtin_amdgcn_global_load_lds(
      reinterpret_cast<u32_as1*>(reinterpret_cast<unsigned long long>(g)),
      reinterpret_cast<u32_as3*>(static_cast<unsigned int>(
          reinterpret_cast<unsigned long long>(l))),
      16, 0, 0);
}

// ---------------------------------------------------------------------------
// pack: 5120 32x32-tile jobs, one per block (HBM-floor ~7 us):
//   jobs [0,4096):     x -> xb (straight bf16) + VT (transpose)
//   jobs [4096,4608):  e -> eb (straight) + ET (transpose)
//   jobs [4608,4864):  Wq -> WqT (transpose)
//   jobs [4864,5120):  Wk -> WkT (transpose)
// ---------------------------------------------------------------------------
__global__ __launch_bounds__(256, 4) void pack_k(
    const float* __restrict__ x, const float* __restrict__ e,
    const float* __restrict__ Wq, const float* __restrict__ Wk, bf16* xb,
    bf16* VT, bf16* eb, bf16* ET, bf16* WqT, bf16* WkT) {
  __shared__ float tile[32][33];
  const int tid  = threadIdx.x;
  const int lrow = tid >> 3;        // 0..31 (load row)
  const int lc4  = (tid & 7) * 4;   // float4 col
  const int j    = blockIdx.x;
  const float* src; int ld;
  bf16 *dS = nullptr, *dT; int ldS = 0, ldT;
  if (j < 4096) {
    int b = j >> 9, r = (j >> 3) & 63, c = j & 7;
    src = x + ((long)b * NN + r * 32) * DIM_X + c * 32; ld = DIM_X;
    dS = xb + ((long)b * NN + r * 32) * DIM_X + c * 32; ldS = DIM_X;
    dT = VT + ((long)b * DIM_X + c * 32) * NN + r * 32; ldT = NN;
  } else if (j < 4608) {
    int i = j - 4096, r = i >> 3, c = i & 7;
    src = e + ((long)r * 32) * DIM_E + c * 32; ld = DIM_E;
    dS = eb + ((long)r * 32) * DIM_E + c * 32; ldS = DIM_E;
    dT = ET + ((long)c * 32) * NN + r * 32; ldT = NN;
  } else if (j < 4864) {
    int i = j - 4608, r = i >> 4, c = i & 15;
    src = Wq + ((long)r * 32) * DD + c * 32; ld = DD;
    dT = WqT + ((long)c * 32) * DD + r * 32; ldT = DD;
  } else {
    int i = j - 4864, r = i >> 4, c = i & 15;
    src = Wk + ((long)r * 32) * DD + c * 32; ld = DD;
    dT = WkT + ((long)c * 32) * DD + r * 32; ldT = DD;
  }
  float4 v = *(const float4*)(src + (long)lrow * ld + lc4);
  if (dS) {
    ushort4 o;
    o.x = f2bf(v.x); o.y = f2bf(v.y); o.z = f2bf(v.z); o.w = f2bf(v.w);
    *(ushort4*)((unsigned short*)dS + (long)lrow * ldS + lc4) = o;
  }
  tile[lrow][lc4 + 0] = v.x; tile[lrow][lc4 + 1] = v.y;
  tile[lrow][lc4 + 2] = v.z; tile[lrow][lc4 + 3] = v.w;
  __syncthreads();
  {
    ushort4 o;
    o.x = f2bf(tile[lc4 + 0][lrow]);
    o.y = f2bf(tile[lc4 + 1][lrow]);
    o.z = f2bf(tile[lc4 + 2][lrow]);
    o.w = f2bf(tile[lc4 + 3][lrow]);
    *(ushort4*)((unsigned short*)dT + (long)lrow * ldT + lc4) = o;
  }
}

// ---------------------------------------------------------------------------
// One BMxBN tile of C = alpha * Acat @ Bcat^T (operands K-major bf16).
// 4 waves 2x2, wave tile (BM/2)x(BN/2), 16x16x32 MFMA, XOR-swizzled LDS,
// global_load_lds width-16 staging, double-buffered (stage t+1 issued before
// compute of t; the single end-of-step barrier's vmcnt(0) drains it after
// the prefetch latency hid under the MFMAs).
// ASPLIT>0: for k>=ASPLIT read A1 at k-ASPLIT (K-concatenation of A0|A1).
// BSPLIT>0: same for B0|B1 (B1==B0 gives a K-repeated B).
// smem must be 2*(BM+BN)*BKt*2 bytes.
// ---------------------------------------------------------------------------
template <int BM, int BN, int BKt, bool OUT_BF16, int ASPLIT, int BSPLIT>
__device__ void gemm_tile(const bf16* __restrict__ A0,
                          const bf16* __restrict__ A1,
                          const bf16* __restrict__ B0,
                          const bf16* __restrict__ B1, void* __restrict__ Cv,
                          int K, int lda, int ldb, int ldc, float alpha,
                          char* smem) {
  constexpr int CPT  = BKt / 8;      // 16B chunks per row
  constexpr int KS   = BKt / 32;     // MFMA k-steps per staged tile
  constexpr int WTM  = BM / 2, WTN = BN / 2;
  constexpr int IM   = WTM / 16, IN = WTN / 16;
  constexpr int CA   = BM * CPT, CB = BN * CPT;
  constexpr int BUFB = (BM + BN) * BKt * 2;  // bytes per LDS buffer

  const int tid  = threadIdx.x;
  const int lane = tid & 63;
  const int wave = tid >> 6;
  const int lm   = lane & 15;
  const int quad = lane >> 4;
  const int wm   = (wave >> 1) * WTM;
  const int wn   = (wave & 1) * WTN;

  auto stage = [&](int t, int buf) {
    const int k0 = t * BKt;
    const bf16* Ak = A0; int ka = k0;
    if (ASPLIT > 0 && k0 >= ASPLIT) { Ak = A1; ka = k0 - ASPLIT; }
    const bf16* Bk = B0; int kb = k0;
    if (BSPLIT > 0 && k0 >= BSPLIT) { Bk = B1; kb = k0 - BSPLIT; }
    bf16* sA = (bf16*)(smem + (size_t)buf * BUFB);
    bf16* sB = sA + BM * BKt;
#pragma unroll
    for (int c = tid; c < CA; c += 256) {
      int row = c / CPT;
      int cb  = (c % CPT) ^ (row % CPT);
      async_lds16(Ak + (long)row * lda + ka + cb * 8, sA + (size_t)c * 8);
    }
#pragma unroll
    for (int c = tid; c < CB; c += 256) {
      int row = c / CPT;
      int cb  = (c % CPT) ^ (row % CPT);
      async_lds16(Bk + (long)row * ldb + kb + cb * 8, sB + (size_t)c * 8);
    }
  };

  f32x4 acc[IM][IN];
#pragma unroll
  for (int i = 0; i < IM; i++)
#pragma unroll
    for (int j = 0; j < IN; j++) acc[i][j] = (f32x4){0.f, 0.f, 0.f, 0.f};

  const int nt = K / BKt;
  stage(0, 0);
  __syncthreads();  // drains vmcnt(0): tile 0 resident
  int cur = 0;
  for (int t = 0; t < nt; ++t) {
    if (t + 1 < nt) stage(t + 1, cur ^ 1);  // prefetch overlaps compute below
    const bf16* sA = (const bf16*)(smem + (size_t)cur * BUFB);
    const bf16* sB = sA + BM * BKt;
    bf16x8 af[KS][IM], bfr[KS][IN];
#pragma unroll
    for (int s = 0; s < KS; s++) {
#pragma unroll
      for (int i = 0; i < IM; i++) {
        int r = wm + i * 16 + lm;
        af[s][i] = *(const bf16x8*)&sA[r * BKt +
                                       (((s * 4 + quad) ^ (r % CPT)) * 8)];
      }
#pragma unroll
      for (int j = 0; j < IN; j++) {
        int r = wn + j * 16 + lm;
        bfr[s][j] = *(const bf16x8*)&sB[r * BKt +
                                        (((s * 4 + quad) ^ (r % CPT)) * 8)];
      }
    }
#pragma unroll
    for (int s = 0; s < KS; s++)
#pragma unroll
      for (int i = 0; i < IM; i++)
#pragma unroll
        for (int j = 0; j < IN; j++)
          acc[i][j] = __builtin_amdgcn_mfma_f32_16x16x32_bf16(
              af[s][i], bfr[s][j], acc[i][j], 0, 0, 0);
    __syncthreads();  // readers done with buf cur; prefetch into cur^1 drained
    cur ^= 1;
  }

  // C/D layout (16x16): col = lane&15, row = (lane>>4)*4 + reg  [m89-verified]
  const int baseRow = wm + quad * 4;
  const int baseCol = wn + lm;
  if (OUT_BF16) {
    bf16* Cb = (bf16*)Cv;
#pragma unroll
    for (int i = 0; i < IM; i++)
#pragma unroll
      for (int r = 0; r < 4; r++) {
        int row = baseRow + i * 16 + r;
#pragma unroll
        for (int j = 0; j < IN; j++)
          Cb[(long)row * ldc + baseCol + j * 16] =
              __float2bfloat16(acc[i][j][r] * alpha);
      }
  } else {
    float* Cf = (float*)Cv;
#pragma unroll
    for (int i = 0; i < IM; i++)
#pragma unroll
      for (int r = 0; r < 4; r++) {
        int row = baseRow + i * 16 + r;
#pragma unroll
        for (int j = 0; j < IN; j++)
          Cf[(long)row * ldc + baseCol + j * 16] = acc[i][j][r] * alpha;
      }
  }
}

// ---------------------------------------------------------------------------
// phase1 (320 blocks, 48KB LDS -> up to 3/CU so the 64 W2T blocks co-schedule
// with M blocks instead of serializing):
//   blocks [0,256):   M half-K partials, 128x64 tiles (16 MFMA / 12 ds_read
//                     per wave-step vs 8/8 at 64x64), 256 jobs
//                     (b, mt in 2 x 128rows, nt in 8 x 64cols, kh in 2),
//                     K=1024 each, reduced in phase2 via K-concat.
//                     b = bx&7 keeps VT_b XCD-L2-affine.
//   blocks [256,320): W2T = WqT @ WkT^T (64x64, K=512)
// ---------------------------------------------------------------------------
__global__ __launch_bounds__(256, 2) void phase1_k(
    const bf16* VT, const bf16* ET, const bf16* WqT, const bf16* WkT,
    bf16* M1, bf16* M2, bf16* W2T) {
  __shared__ __align__(16) char smem[49152];
  const int bx = blockIdx.x;
  if (bx < 256) {
    const int b   = bx & 7;
    const int idx = bx >> 3;              // 0..31
    const int kh  = idx & 1;              // K half
    const int mt  = (idx >> 1) & 1;       // row tile (2 x 128 = 256)
    const int nt  = idx >> 2;             // col tile (8 x 64 = 512)
    const bf16* A = VT + (long)b * DIM_X * NN + (long)mt * 128 * NN +
                    kh * 1024;
    const bf16* B = (nt < 4)
        ? VT + (long)b * DIM_X * NN + (long)nt * 64 * NN + kh * 1024
        : ET + (long)(nt - 4) * 64 * NN + kh * 1024;
    bf16* C = (kh ? M2 : M1) + (long)b * DIM_X * DD + (long)mt * 128 * DD +
              nt * 64;
    gemm_tile<128, 64, 64, true, 0, 0>(A, nullptr, B, nullptr, C, 1024, NN,
                                       NN, DD, 1.0f, smem);
  } else {
    const int i = bx - 256;
    int r2 = i >> 3, c2 = i & 7;
    gemm_tile<64, 64, 64, true, 0, 0>(
        WqT + (long)r2 * 64 * DD, nullptr, WkT + (long)c2 * 64 * DD, nullptr,
        W2T + (long)r2 * 64 * DD + c2 * 64, DD, DD, DD, DD, 1.0f, smem);
  }
}

// ---------------------------------------------------------------------------
// phase2 (512 blocks): R = SCALE * (M1+M2) @ W2T^T as K-concat GEMM K=1024
// ([M1|M2] @ [W2T|W2T]^T, ASPLIT=BSPLIT=512; verified in rounds 1-2).
// 32x64 tiles, BK=128 dbuf (48KB), 2/CU resident.
// ---------------------------------------------------------------------------
__global__ __launch_bounds__(256, 3) void phase2_k(const bf16* M1,
                                                   const bf16* M2,
                                                   const bf16* W2T, bf16* R) {
  __shared__ __align__(16) char smem[49152];
  const int bx = blockIdx.x;
  const int b = bx & 7, r = (bx >> 3) & 7, c = bx >> 6;
  const bf16* a0 = M1 + (long)b * DIM_X * DD + (long)r * 32 * DD;
  const bf16* a1 = M2 + (long)b * DIM_X * DD + (long)r * 32 * DD;
  const bf16* w  = W2T + (long)c * 64 * DD;
  gemm_tile<32, 64, 128, true, 512, 512>(
      a0, a1, w, w, R + (long)b * DIM_X * DD + (long)r * 32 * DD + c * 64,
      1024, DD, DD, DD, SCALE, smem);
}

// ---------------------------------------------------------------------------
// phase3 (256 blocks): out = [xb|eb] @ R^T, 128x128 tiles (the exact m97
// per-wave shape: 64x64 wave tile, 32 MFMA / 16 ds_read per step), BK=64
// dbuf = 64KB LDS, fp32 out, 1 block/CU, all 256 CUs busy. B-staging
// traffic halves vs 64x128 (67 MB vs 100 MB). XCD-affine b = bx&7.
// ---------------------------------------------------------------------------
__global__ __launch_bounds__(256, 2) void phase3_k(const bf16* xb,
                                                   const bf16* eb,
                                                   const bf16* R, float* out) {
  __shared__ __align__(16) char smem[65536];
  const int bx = blockIdx.x;
  const int b = bx & 7, m = (bx >> 3) & 15, n = (bx >> 7) & 1;
  gemm_tile<128, 128, 64, false, 256, 0>(
      xb + (long)b * NN * DIM_X + (long)m * 128 * DIM_X,
      eb + (long)m * 128 * DIM_E,
      R + (long)b * DIM_X * DD + (long)n * 128 * DD, nullptr,
      out + (long)b * NN * DIM_X + (long)m * 128 * DIM_X + n * 128, DD,
      DIM_X, DD, DIM_X, 1.0f, smem);
}

// ---------------------------------------------------------------------------

extern "C" void kernel_launch(void* const* d_in, const int* in_sizes, int n_in,
                              void* d_out, int out_size, void* d_ws,
                              size_t ws_size, hipStream_t stream) {
  const float* x  = (const float*)d_in[0];  // (8, 2048, 256)
  const float* e  = (const float*)d_in[1];  // (2048, 256)
  const float* Wq = (const float*)d_in[2];  // (512, 512)
  const float* Wk = (const float*)d_in[3];  // (512, 512)
  float* out = (float*)d_out;               // (8, 2048, 256)

  char* ws = (char*)d_ws;
  size_t off = 0;
  auto alloc = [&](size_t bytes) {
    void* p = ws + off;
    off += (bytes + 255) & ~(size_t)255;
    return p;
  };

  bf16* xb  = (bf16*)alloc((size_t)NB * NN * DIM_X * 2);  // 8.4 MB
  bf16* VT  = (bf16*)alloc((size_t)NB * DIM_X * NN * 2);  // 8.4 MB
  bf16* eb  = (bf16*)alloc((size_t)NN * DIM_E * 2);       // 1 MB
  bf16* ET  = (bf16*)alloc((size_t)DIM_E * NN * 2);       // 1 MB
  bf16* WqT = (bf16*)alloc((size_t)DD * DD * 2);          // 0.5 MB
  bf16* WkT = (bf16*)alloc((size_t)DD * DD * 2);          // 0.5 MB
  bf16* W2T = (bf16*)alloc((size_t)DD * DD * 2);          // 0.5 MB
  bf16* M1  = (bf16*)alloc((size_t)NB * DIM_X * DD * 2);  // 2 MB
  bf16* M2  = (bf16*)alloc((size_t)NB * DIM_X * DD * 2);  // 2 MB
  bf16* R   = (bf16*)alloc((size_t)NB * DIM_X * DD * 2);  // 2 MB

  pack_k<<<5120, 256, 0, stream>>>(x, e, Wq, Wk, xb, VT, eb, ET, WqT, WkT);
  phase1_k<<<320, 256, 0, stream>>>(VT, ET, WqT, WkT, M1, M2, W2T);
  phase2_k<<<512, 256, 0, stream>>>(M1, M2, W2T, R);
  phase3_k<<<256, 256, 0, stream>>>(xb, eb, R, out);
}